// Round 2
// baseline (346.400 us; speedup 1.0000x reference)
//
#include <hip/hip_runtime.h>
#include <hip/hip_bf16.h>

typedef __attribute__((ext_vector_type(8))) __bf16 bf16x8;
typedef __attribute__((ext_vector_type(4))) __bf16 bf16x4;
typedef __attribute__((ext_vector_type(4))) float f32x4;

#define BDIM 2
#define TSEQ 2048
#define CDIM 2048
#define NH 16
#define NKV 4
#define HD 128
#define WIN 512

// async global->LDS, 16B per lane; LDS dest is wave-uniform base + lane*16
__device__ __forceinline__ void gl_lds16(const __bf16* g, __bf16* l) {
  __builtin_amdgcn_global_load_lds(
      (const __attribute__((address_space(1))) void*)g,
      (__attribute__((address_space(3))) void*)l, 16, 0, 0);
}

// ---------------------------------------------------------------------------
// RMSNorm: x (f32 [4096][2048]) -> xn (bf16), one block per row
// ---------------------------------------------------------------------------
__global__ __launch_bounds__(256) void k_rmsnorm(const float* __restrict__ x,
                                                 const float* __restrict__ w,
                                                 __bf16* __restrict__ xn) {
  __shared__ float red[4];
  const int row = blockIdx.x;
  const int tid = threadIdx.x;
  const float* xr = x + (size_t)row * CDIM;
  f32x4 v0 = *reinterpret_cast<const f32x4*>(&xr[tid * 8]);
  f32x4 v1 = *reinterpret_cast<const f32x4*>(&xr[tid * 8 + 4]);
  float s = v0[0] * v0[0] + v0[1] * v0[1] + v0[2] * v0[2] + v0[3] * v0[3] +
            v1[0] * v1[0] + v1[1] * v1[1] + v1[2] * v1[2] + v1[3] * v1[3];
#pragma unroll
  for (int off = 32; off > 0; off >>= 1) s += __shfl_down(s, off, 64);
  if ((tid & 63) == 0) red[tid >> 6] = s;
  __syncthreads();
  float tot = red[0] + red[1] + red[2] + red[3];
  float nrm = rsqrtf(tot * (1.0f / CDIM) + 1e-6f);
  const float* wp = w + tid * 8;
  bf16x8 o;
  o[0] = (__bf16)(v0[0] * nrm * wp[0]);
  o[1] = (__bf16)(v0[1] * nrm * wp[1]);
  o[2] = (__bf16)(v0[2] * nrm * wp[2]);
  o[3] = (__bf16)(v0[3] * nrm * wp[3]);
  o[4] = (__bf16)(v1[0] * nrm * wp[4]);
  o[5] = (__bf16)(v1[1] * nrm * wp[5]);
  o[6] = (__bf16)(v1[2] * nrm * wp[6]);
  o[7] = (__bf16)(v1[3] * nrm * wp[7]);
  *reinterpret_cast<bf16x8*>(&xn[(size_t)row * CDIM + tid * 8]) = o;
}

// ---------------------------------------------------------------------------
// Weight transpose+convert: W f32 [K=2048][N] -> Wt bf16 [N][2048]
// ---------------------------------------------------------------------------
__global__ __launch_bounds__(256) void k_wtrans(const float* __restrict__ W,
                                                __bf16* __restrict__ Wt, int N) {
  __shared__ float lt[64][65];
  const int tid = threadIdx.x;
  const int n0 = blockIdx.x * 64, k0 = blockIdx.y * 64;
  const int tr = tid >> 4, tc = tid & 15;
#pragma unroll
  for (int i = 0; i < 4; ++i) {
    int kr = tr + i * 16;
    f32x4 vv = *reinterpret_cast<const f32x4*>(&W[(size_t)(k0 + kr) * N + n0 + tc * 4]);
    lt[kr][tc * 4 + 0] = vv[0];
    lt[kr][tc * 4 + 1] = vv[1];
    lt[kr][tc * 4 + 2] = vv[2];
    lt[kr][tc * 4 + 3] = vv[3];
  }
  __syncthreads();
#pragma unroll
  for (int i = 0; i < 4; ++i) {
    int nr = tr + i * 16;
    int kc = tc * 4;
    bf16x4 o;
    o[0] = (__bf16)lt[kc + 0][nr];
    o[1] = (__bf16)lt[kc + 1][nr];
    o[2] = (__bf16)lt[kc + 2][nr];
    o[3] = (__bf16)lt[kc + 3][nr];
    *reinterpret_cast<bf16x4*>(&Wt[(size_t)(n0 + nr) * 2048 + k0 + kc]) = o;
  }
}

// ---------------------------------------------------------------------------
// RoPE in-place on Q (bf16 [B][16][T][128]) and K (bf16 [B][4][T][128]).
// ---------------------------------------------------------------------------
__global__ __launch_bounds__(256) void k_rope(__bf16* __restrict__ Q,
                                              __bf16* __restrict__ K,
                                              const float* __restrict__ rc,
                                              const float* __restrict__ rs) {
  int g = blockIdx.x * 4 + (threadIdx.x >> 6);
  int lane = threadIdx.x & 63;
  int b = g / (TSEQ * (NH + NKV));
  int rem = g % (TSEQ * (NH + NKV));
  int t = rem / (NH + NKV);
  int hh = rem % (NH + NKV);
  __bf16* base;
  if (hh < NH)
    base = Q + (((size_t)(b * NH + hh)) * TSEQ + t) * HD;
  else
    base = K + (((size_t)(b * NKV + (hh - NH))) * TSEQ + t) * HD;
  float x1 = (float)base[lane];
  float x2 = (float)base[lane + 64];
  float c = rc[t * 64 + lane];
  float s = rs[t * 64 + lane];
  base[lane] = (__bf16)(x1 * c - x2 * s);
  base[lane + 64] = (__bf16)(x2 * c + x1 * s);
}

// ---------------------------------------------------------------------------
// GEMM QKV (m97 structure): C[4096][3072] = xn @ [wq|wk|wv]^T, B given [N][K].
// 128x128 tile, BK=32, global_load_lds width-16, linear LDS.
// Epilogue scatters Q,K row-major (b,h,t,d) and V TRANSPOSED (b,h,d,t).
// ---------------------------------------------------------------------------
__global__ __launch_bounds__(256) void k_gemm_qkv(
    const __bf16* __restrict__ xn, const __bf16* __restrict__ wqT,
    const __bf16* __restrict__ wkT, const __bf16* __restrict__ wvT,
    __bf16* __restrict__ Q, __bf16* __restrict__ K, __bf16* __restrict__ VT) {
  __shared__ __align__(16) __bf16 lA[128 * 32];
  __shared__ __align__(16) __bf16 lB[128 * 32];
  const int tid = threadIdx.x;
  const int lane = tid & 63;
  const int w = tid >> 6;
  const int wrow = (w >> 1) * 64, wcol = (w & 1) * 64;
  const int l16 = lane & 15, lhi = lane >> 4;
  const int grow = lane >> 2;        // 0..15
  const int gcol = (lane & 3) * 8;   // elem offset within BK
  const int m0 = blockIdx.y * 128;
  const int n0 = blockIdx.x * 128;
  const __bf16* wt;
  int nrel;
  if (n0 < 2048) { wt = wqT; nrel = n0; }
  else if (n0 < 2560) { wt = wkT; nrel = n0 - 2048; }
  else { wt = wvT; nrel = n0 - 2560; }

  f32x4 acc[4][4] = {};

  for (int k0 = 0; k0 < CDIM; k0 += 32) {
#pragma unroll
    for (int i = 0; i < 2; ++i) {
      const int r0 = (w * 2 + i) * 16;
      gl_lds16(&xn[(size_t)(m0 + r0 + grow) * CDIM + k0 + gcol], &lA[r0 * 32]);
      gl_lds16(&wt[(size_t)(nrel + r0 + grow) * CDIM + k0 + gcol], &lB[r0 * 32]);
    }
    __syncthreads();
    bf16x8 a[4], b[4];
#pragma unroll
    for (int mi = 0; mi < 4; ++mi)
      a[mi] = *reinterpret_cast<const bf16x8*>(&lA[(wrow + mi * 16 + l16) * 32 + lhi * 8]);
#pragma unroll
    for (int ni = 0; ni < 4; ++ni)
      b[ni] = *reinterpret_cast<const bf16x8*>(&lB[(wcol + ni * 16 + l16) * 32 + lhi * 8]);
#pragma unroll
    for (int mi = 0; mi < 4; ++mi)
#pragma unroll
      for (int ni = 0; ni < 4; ++ni)
        acc[mi][ni] = __builtin_amdgcn_mfma_f32_16x16x32_bf16(a[mi], b[ni], acc[mi][ni], 0, 0, 0);
    __syncthreads();
  }

#pragma unroll
  for (int mi = 0; mi < 4; ++mi) {
#pragma unroll
    for (int ni = 0; ni < 4; ++ni) {
#pragma unroll
      for (int r = 0; r < 4; ++r) {
        int row = m0 + wrow + mi * 16 + lhi * 4 + r;
        int col = n0 + wcol + ni * 16 + l16;
        int bb = row >> 11, t = row & 2047;
        __bf16 hv = (__bf16)acc[mi][ni][r];
        if (col < 2048) {
          int h = col >> 7, d = col & 127;
          Q[(((size_t)(bb * NH + h)) * TSEQ + t) * HD + d] = hv;
        } else if (col < 2560) {
          int h = (col - 2048) >> 7, d = col & 127;
          K[(((size_t)(bb * NKV + h)) * TSEQ + t) * HD + d] = hv;
        } else {
          int h = (col - 2560) >> 7, d = col & 127;
          VT[(((size_t)(bb * NKV + h)) * HD + d) * TSEQ + t] = hv;
        }
      }
    }
  }
}

// ---------------------------------------------------------------------------
// Flash attention, sliding window 512, causal, GQA 16/4.
// Block: (b,h, 64 q rows); 4 waves x 16 q rows. KV tiles of 64.
// V is consumed pre-transposed from global: VT[b][kvh][d][T].
// ---------------------------------------------------------------------------
__global__ __launch_bounds__(256) void k_attn(const __bf16* __restrict__ Q,
                                              const __bf16* __restrict__ K,
                                              const __bf16* __restrict__ VT,
                                              __bf16* __restrict__ Aout) {
  __shared__ __align__(16) __bf16 lK[64][136];
  __shared__ __align__(16) __bf16 lVt[128][72];
  __shared__ __align__(16) __bf16 lP[4][16][72];

  const int tid = threadIdx.x, lane = tid & 63, wid = tid >> 6;
  const int l16 = lane & 15, lhi = lane >> 4;
  const int bh = blockIdx.y;
  const int b = bh >> 4, h = bh & 15;
  const int kvh = h >> 2;
  const int q0 = blockIdx.x * 64;
  const int qw = q0 + wid * 16;

  const __bf16* Qb = Q + (size_t)bh * TSEQ * HD;
  const __bf16* Kb = K + (size_t)(b * NKV + kvh) * TSEQ * HD;
  const __bf16* Vt = VT + (size_t)(b * NKV + kvh) * HD * TSEQ;

  bf16x8 aq[4];
#pragma unroll
  for (int dblk = 0; dblk < 4; ++dblk)
    aq[dblk] = *reinterpret_cast<const bf16x8*>(&Qb[(size_t)(qw + l16) * HD + dblk * 32 + lhi * 8]);

  float mrow[4], lrow[4];
#pragma unroll
  for (int r = 0; r < 4; ++r) { mrow[r] = -INFINITY; lrow[r] = 0.0f; }
  f32x4 accO[8] = {};

  int s_lo = q0 - (WIN - 1);
  if (s_lo < 0) s_lo = 0;
  s_lo &= ~63;
  const float scale = 0.08838834764831845f;  // 1/sqrt(128)

  for (int s0 = s_lo; s0 < q0 + 64; s0 += 64) {
    // stage K [64][128] row-major and V^T [128][64] (vectorized b128 writes)
#pragma unroll
    for (int i = 0; i < 4; ++i) {
      int slot = tid + i * 256;
      int kr = slot >> 4, kc = (slot & 15) * 8;
      *reinterpret_cast<bf16x8*>(&lK[kr][kc]) =
          *reinterpret_cast<const bf16x8*>(&Kb[(size_t)(s0 + kr) * HD + kc]);
      int vd = slot >> 3, vc = (slot & 7) * 8;
      *reinterpret_cast<bf16x8*>(&lVt[vd][vc]) =
          *reinterpret_cast<const bf16x8*>(&Vt[(size_t)vd * TSEQ + s0 + vc]);
    }
    __syncthreads();

    // QK^T: 16 q x 64 s
    f32x4 accS[4] = {};
#pragma unroll
    for (int sb = 0; sb < 4; ++sb) {
#pragma unroll
      for (int dblk = 0; dblk < 4; ++dblk) {
        bf16x8 bk = *reinterpret_cast<const bf16x8*>(&lK[sb * 16 + l16][dblk * 32 + lhi * 8]);
        accS[sb] = __builtin_amdgcn_mfma_f32_16x16x32_bf16(aq[dblk], bk, accS[sb], 0, 0, 0);
      }
    }

    // mask + online softmax; this lane covers rows qw + lhi*4 + r, s cols s0+sb*16+l16
#pragma unroll
    for (int r = 0; r < 4; ++r) {
      int qrow = qw + lhi * 4 + r;
      float vv[4];
      float tmax = -INFINITY;
#pragma unroll
      for (int sb = 0; sb < 4; ++sb) {
        int sc = s0 + sb * 16 + l16;
        float val = accS[sb][r] * scale;
        bool ok = (sc <= qrow) && (qrow - sc < WIN);
        vv[sb] = ok ? val : -INFINITY;
        tmax = fmaxf(tmax, vv[sb]);
      }
#pragma unroll
      for (int off = 1; off < 16; off <<= 1) tmax = fmaxf(tmax, __shfl_xor(tmax, off, 64));
      float mnew = fmaxf(mrow[r], tmax);
      float msafe = (mnew == -INFINITY) ? 0.0f : mnew;
      float corr = (mrow[r] == mnew) ? 1.0f : __expf(mrow[r] - mnew);
      float psum = 0.0f;
#pragma unroll
      for (int sb = 0; sb < 4; ++sb) {
        float p = __expf(vv[sb] - msafe);
        vv[sb] = p;
        psum += p;
      }
#pragma unroll
      for (int off = 1; off < 16; off <<= 1) psum += __shfl_xor(psum, off, 64);
      lrow[r] = lrow[r] * corr + psum;
      mrow[r] = mnew;
#pragma unroll
      for (int ni = 0; ni < 8; ++ni) accO[ni][r] *= corr;
#pragma unroll
      for (int sb = 0; sb < 4; ++sb)
        lP[wid][lhi * 4 + r][sb * 16 + l16] = (__bf16)vv[sb];
    }

    // P (C/D layout in LDS) -> A-operand frags; PV
    bf16x8 ap[2];
#pragma unroll
    for (int ks = 0; ks < 2; ++ks)
      ap[ks] = *reinterpret_cast<const bf16x8*>(&lP[wid][l16][ks * 32 + lhi * 8]);
#pragma unroll
    for (int ni = 0; ni < 8; ++ni) {
#pragma unroll
      for (int ks = 0; ks < 2; ++ks) {
        bf16x8 bv = *reinterpret_cast<const bf16x8*>(&lVt[ni * 16 + l16][ks * 32 + lhi * 8]);
        accO[ni] = __builtin_amdgcn_mfma_f32_16x16x32_bf16(ap[ks], bv, accO[ni], 0, 0, 0);
      }
    }
    __syncthreads();
  }

  float invl[4];
#pragma unroll
  for (int r = 0; r < 4; ++r) invl[r] = 1.0f / lrow[r];
#pragma unroll
  for (int ni = 0; ni < 8; ++ni) {
#pragma unroll
    for (int r = 0; r < 4; ++r) {
      int row = qw + lhi * 4 + r;
      int d = ni * 16 + l16;
      Aout[((size_t)(b * TSEQ + row)) * CDIM + h * HD + d] = (__bf16)(accO[ni][r] * invl[r]);
    }
  }
}

// ---------------------------------------------------------------------------
// Output GEMM + residual (m97 structure): out f32 = x + A @ woT^T
// ---------------------------------------------------------------------------
__global__ __launch_bounds__(256) void k_gemm_out(const __bf16* __restrict__ A,
                                                  const __bf16* __restrict__ woT,
                                                  const float* __restrict__ x,
                                                  float* __restrict__ out) {
  __shared__ __align__(16) __bf16 lA[128 * 32];
  __shared__ __align__(16) __bf16 lB[128 * 32];
  const int tid = threadIdx.x;
  const int lane = tid & 63;
  const int w = tid >> 6;
  const int wrow = (w >> 1) * 64, wcol = (w & 1) * 64;
  const int l16 = lane & 15, lhi = lane >> 4;
  const int grow = lane >> 2;
  const int gcol = (lane & 3) * 8;
  const int m0 = blockIdx.y * 128;
  const int n0 = blockIdx.x * 128;

  f32x4 acc[4][4] = {};

  for (int k0 = 0; k0 < CDIM; k0 += 32) {
#pragma unroll
    for (int i = 0; i < 2; ++i) {
      const int r0 = (w * 2 + i) * 16;
      gl_lds16(&A[(size_t)(m0 + r0 + grow) * CDIM + k0 + gcol], &lA[r0 * 32]);
      gl_lds16(&woT[(size_t)(n0 + r0 + grow) * CDIM + k0 + gcol], &lB[r0 * 32]);
    }
    __syncthreads();
    bf16x8 a[4], b[4];
#pragma unroll
    for (int mi = 0; mi < 4; ++mi)
      a[mi] = *reinterpret_cast<const bf16x8*>(&lA[(wrow + mi * 16 + l16) * 32 + lhi * 8]);
#pragma unroll
    for (int ni = 0; ni < 4; ++ni)
      b[ni] = *reinterpret_cast<const bf16x8*>(&lB[(wcol + ni * 16 + l16) * 32 + lhi * 8]);
#pragma unroll
    for (int mi = 0; mi < 4; ++mi)
#pragma unroll
      for (int ni = 0; ni < 4; ++ni)
        acc[mi][ni] = __builtin_amdgcn_mfma_f32_16x16x32_bf16(a[mi], b[ni], acc[mi][ni], 0, 0, 0);
    __syncthreads();
  }

#pragma unroll
  for (int mi = 0; mi < 4; ++mi) {
#pragma unroll
    for (int ni = 0; ni < 4; ++ni) {
#pragma unroll
      for (int r = 0; r < 4; ++r) {
        int row = m0 + wrow + mi * 16 + lhi * 4 + r;
        int col = n0 + wcol + ni * 16 + l16;
        size_t idx = (size_t)row * CDIM + col;
        out[idx] = x[idx] + acc[mi][ni][r];
      }
    }
  }
}

// ---------------------------------------------------------------------------
extern "C" void kernel_launch(void* const* d_in, const int* in_sizes, int n_in,
                              void* d_out, int out_size, void* d_ws, size_t ws_size,
                              hipStream_t stream) {
  const float* x = (const float*)d_in[0];
  const float* norm_w = (const float*)d_in[1];
  const float* wq = (const float*)d_in[2];
  const float* wk = (const float*)d_in[3];
  const float* wv = (const float*)d_in[4];
  const float* wo = (const float*)d_in[5];
  const float* rc = (const float*)d_in[6];
  const float* rs = (const float*)d_in[7];
  float* out = (float*)d_out;

  char* ws = (char*)d_ws;
  __bf16* xn  = (__bf16*)(ws);              // 4096x2048 bf16 (reused as attn_out)
  __bf16* wqT = (__bf16*)(ws + 16777216);   // 2048x2048
  __bf16* wkT = (__bf16*)(ws + 25165824);   // 512x2048
  __bf16* wvT = (__bf16*)(ws + 27262976);   // 512x2048
  __bf16* woT = (__bf16*)(ws + 29360128);   // 2048x2048
  __bf16* Qb  = (__bf16*)(ws + 37748736);   // 2x16x2048x128
  __bf16* Kb  = (__bf16*)(ws + 54525952);   // 2x4x2048x128
  __bf16* VTb = (__bf16*)(ws + 58720256);   // 2x4x128x2048 (transposed)
  if (ws_size < 62914560) return;

  k_wtrans<<<dim3(32, 32), 256, 0, stream>>>(wq, wqT, 2048);
  k_wtrans<<<dim3(8, 32), 256, 0, stream>>>(wk, wkT, 512);
  k_wtrans<<<dim3(8, 32), 256, 0, stream>>>(wv, wvT, 512);
  k_wtrans<<<dim3(32, 32), 256, 0, stream>>>(wo, woT, 2048);
  k_rmsnorm<<<4096, 256, 0, stream>>>(x, norm_w, xn);
  k_gemm_qkv<<<dim3(24, 32), 256, 0, stream>>>(xn, wqT, wkT, wvT, Qb, Kb, VTb);
  k_rope<<<(BDIM * TSEQ * (NH + NKV)) / 4, 256, 0, stream>>>(Qb, Kb, rc, rs);
  k_attn<<<dim3(TSEQ / 64, BDIM * NH), 256, 0, stream>>>(Qb, Kb, VTb, xn);
  k_gemm_out<<<dim3(16, 32), 256, 0, stream>>>(xn, woT, x, out);
}

// Round 3
// 330.768 us; speedup vs baseline: 1.0473x; 1.0473x over previous
//
#include <hip/hip_runtime.h>
#include <hip/hip_bf16.h>

typedef __attribute__((ext_vector_type(8))) __bf16 bf16x8;
typedef __attribute__((ext_vector_type(4))) __bf16 bf16x4;
typedef __attribute__((ext_vector_type(4))) float f32x4;

#define BDIM 2
#define TSEQ 2048
#define CDIM 2048
#define NH 16
#define NKV 4
#define HD 128
#define WIN 512

// async global->LDS, 16B per lane; LDS dest is wave-uniform base + lane*16
__device__ __forceinline__ void gl_lds16(const __bf16* g, __bf16* l) {
  __builtin_amdgcn_global_load_lds(
      (const __attribute__((address_space(1))) void*)g,
      (__attribute__((address_space(3))) void*)l, 16, 0, 0);
}

// ---------------------------------------------------------------------------
// RMSNorm: x (f32 [4096][2048]) -> xn (bf16), one block per row
// ---------------------------------------------------------------------------
__global__ __launch_bounds__(256) void k_rmsnorm(const float* __restrict__ x,
                                                 const float* __restrict__ w,
                                                 __bf16* __restrict__ xn) {
  __shared__ float red[4];
  const int row = blockIdx.x;
  const int tid = threadIdx.x;
  const float* xr = x + (size_t)row * CDIM;
  f32x4 v0 = *reinterpret_cast<const f32x4*>(&xr[tid * 8]);
  f32x4 v1 = *reinterpret_cast<const f32x4*>(&xr[tid * 8 + 4]);
  float s = v0[0] * v0[0] + v0[1] * v0[1] + v0[2] * v0[2] + v0[3] * v0[3] +
            v1[0] * v1[0] + v1[1] * v1[1] + v1[2] * v1[2] + v1[3] * v1[3];
#pragma unroll
  for (int off = 32; off > 0; off >>= 1) s += __shfl_down(s, off, 64);
  if ((tid & 63) == 0) red[tid >> 6] = s;
  __syncthreads();
  float tot = red[0] + red[1] + red[2] + red[3];
  float nrm = rsqrtf(tot * (1.0f / CDIM) + 1e-6f);
  const float* wp = w + tid * 8;
  bf16x8 o;
  o[0] = (__bf16)(v0[0] * nrm * wp[0]);
  o[1] = (__bf16)(v0[1] * nrm * wp[1]);
  o[2] = (__bf16)(v0[2] * nrm * wp[2]);
  o[3] = (__bf16)(v0[3] * nrm * wp[3]);
  o[4] = (__bf16)(v1[0] * nrm * wp[4]);
  o[5] = (__bf16)(v1[1] * nrm * wp[5]);
  o[6] = (__bf16)(v1[2] * nrm * wp[6]);
  o[7] = (__bf16)(v1[3] * nrm * wp[7]);
  *reinterpret_cast<bf16x8*>(&xn[(size_t)row * CDIM + tid * 8]) = o;
}

// ---------------------------------------------------------------------------
// Weight transpose+convert, all 4 weights in ONE launch.
// W f32 [K=2048][N] -> Wt bf16 [N][2048]; 64x64 tile per block.
// blockIdx.x: 0-31 wq | 32-39 wk | 40-47 wv | 48-79 wo
// ---------------------------------------------------------------------------
__global__ __launch_bounds__(256) void k_wtrans_all(
    const float* __restrict__ wq, const float* __restrict__ wk,
    const float* __restrict__ wv, const float* __restrict__ wo,
    __bf16* __restrict__ wqT, __bf16* __restrict__ wkT,
    __bf16* __restrict__ wvT, __bf16* __restrict__ woT) {
  __shared__ float lt[64][65];
  const int bx = blockIdx.x;
  const float* W;
  __bf16* Wt;
  int N, ntile;
  if (bx < 32) { W = wq; Wt = wqT; N = 2048; ntile = bx; }
  else if (bx < 40) { W = wk; Wt = wkT; N = 512; ntile = bx - 32; }
  else if (bx < 48) { W = wv; Wt = wvT; N = 512; ntile = bx - 40; }
  else { W = wo; Wt = woT; N = 2048; ntile = bx - 48; }
  const int tid = threadIdx.x;
  const int n0 = ntile * 64, k0 = blockIdx.y * 64;
  const int tr = tid >> 4, tc = tid & 15;
#pragma unroll
  for (int i = 0; i < 4; ++i) {
    int kr = tr + i * 16;
    f32x4 vv = *reinterpret_cast<const f32x4*>(&W[(size_t)(k0 + kr) * N + n0 + tc * 4]);
    lt[kr][tc * 4 + 0] = vv[0];
    lt[kr][tc * 4 + 1] = vv[1];
    lt[kr][tc * 4 + 2] = vv[2];
    lt[kr][tc * 4 + 3] = vv[3];
  }
  __syncthreads();
#pragma unroll
  for (int i = 0; i < 4; ++i) {
    int nr = tr + i * 16;
    int kc = tc * 4;
    bf16x4 o;
    o[0] = (__bf16)lt[kc + 0][nr];
    o[1] = (__bf16)lt[kc + 1][nr];
    o[2] = (__bf16)lt[kc + 2][nr];
    o[3] = (__bf16)lt[kc + 3][nr];
    *reinterpret_cast<bf16x4*>(&Wt[(size_t)(n0 + nr) * 2048 + k0 + kc]) = o;
  }
}

// ---------------------------------------------------------------------------
// RoPE in-place on Q (bf16 [B][16][T][128]) and K (bf16 [B][4][T][128]).
// ---------------------------------------------------------------------------
__global__ __launch_bounds__(256) void k_rope(__bf16* __restrict__ Q,
                                              __bf16* __restrict__ K,
                                              const float* __restrict__ rc,
                                              const float* __restrict__ rs) {
  int g = blockIdx.x * 4 + (threadIdx.x >> 6);
  int lane = threadIdx.x & 63;
  int b = g / (TSEQ * (NH + NKV));
  int rem = g % (TSEQ * (NH + NKV));
  int t = rem / (NH + NKV);
  int hh = rem % (NH + NKV);
  __bf16* base;
  if (hh < NH)
    base = Q + (((size_t)(b * NH + hh)) * TSEQ + t) * HD;
  else
    base = K + (((size_t)(b * NKV + (hh - NH))) * TSEQ + t) * HD;
  float x1 = (float)base[lane];
  float x2 = (float)base[lane + 64];
  float c = rc[t * 64 + lane];
  float s = rs[t * 64 + lane];
  base[lane] = (__bf16)(x1 * c - x2 * s);
  base[lane + 64] = (__bf16)(x2 * c + x1 * s);
}

// ---------------------------------------------------------------------------
// GEMM QKV (m97 structure): C[4096][3072] = xn @ [wq|wk|wv]^T, B given [N][K].
// 128x128 tile, BK=32, global_load_lds width-16, linear LDS.
// Epilogue: Q,K scatter row-major (b,h,t,d); V written TRANSPOSED (b,h,d,t)
// via LDS transpose for coalesced stores.
// ---------------------------------------------------------------------------
__global__ __launch_bounds__(256) void k_gemm_qkv(
    const __bf16* __restrict__ xn, const __bf16* __restrict__ wqT,
    const __bf16* __restrict__ wkT, const __bf16* __restrict__ wvT,
    __bf16* __restrict__ Q, __bf16* __restrict__ K, __bf16* __restrict__ VT) {
  // lmem: during K-loop, lA = lmem[0..4095], lB = lmem[4096..8191]
  // after loop (V blocks only), reused as lCt[128][136] transpose buffer
  __shared__ __align__(16) __bf16 lmem[128 * 136];
  __bf16* lA = lmem;
  __bf16* lB = lmem + 128 * 32;
  const int tid = threadIdx.x;
  const int lane = tid & 63;
  const int w = tid >> 6;
  const int wrow = (w >> 1) * 64, wcol = (w & 1) * 64;
  const int l16 = lane & 15, lhi = lane >> 4;
  const int grow = lane >> 2;        // 0..15
  const int gcol = (lane & 3) * 8;   // elem offset within BK
  const int m0 = blockIdx.y * 128;
  const int n0 = blockIdx.x * 128;
  const __bf16* wt;
  int nrel;
  if (n0 < 2048) { wt = wqT; nrel = n0; }
  else if (n0 < 2560) { wt = wkT; nrel = n0 - 2048; }
  else { wt = wvT; nrel = n0 - 2560; }

  f32x4 acc[4][4] = {};

  for (int k0 = 0; k0 < CDIM; k0 += 32) {
#pragma unroll
    for (int i = 0; i < 2; ++i) {
      const int r0 = (w * 2 + i) * 16;
      gl_lds16(&xn[(size_t)(m0 + r0 + grow) * CDIM + k0 + gcol], &lA[r0 * 32]);
      gl_lds16(&wt[(size_t)(nrel + r0 + grow) * CDIM + k0 + gcol], &lB[r0 * 32]);
    }
    __syncthreads();
    bf16x8 a[4], b[4];
#pragma unroll
    for (int mi = 0; mi < 4; ++mi)
      a[mi] = *reinterpret_cast<const bf16x8*>(&lA[(wrow + mi * 16 + l16) * 32 + lhi * 8]);
#pragma unroll
    for (int ni = 0; ni < 4; ++ni)
      b[ni] = *reinterpret_cast<const bf16x8*>(&lB[(wcol + ni * 16 + l16) * 32 + lhi * 8]);
#pragma unroll
    for (int mi = 0; mi < 4; ++mi)
#pragma unroll
      for (int ni = 0; ni < 4; ++ni)
        acc[mi][ni] = __builtin_amdgcn_mfma_f32_16x16x32_bf16(a[mi], b[ni], acc[mi][ni], 0, 0, 0);
    __syncthreads();
  }

  const int bb = m0 >> 11;  // batch (rows m0..m0+127 share it)
  if (n0 < 2560) {
    // Q or K: direct scatter (block-uniform branch)
#pragma unroll
    for (int mi = 0; mi < 4; ++mi) {
#pragma unroll
      for (int ni = 0; ni < 4; ++ni) {
#pragma unroll
        for (int r = 0; r < 4; ++r) {
          int row = m0 + wrow + mi * 16 + lhi * 4 + r;
          int col = n0 + wcol + ni * 16 + l16;
          int t = row & 2047;
          __bf16 hv = (__bf16)acc[mi][ni][r];
          if (n0 < 2048) {
            int h = col >> 7, d = col & 127;
            Q[(((size_t)(bb * NH + h)) * TSEQ + t) * HD + d] = hv;
          } else {
            int h = (col - 2048) >> 7, d = col & 127;
            K[(((size_t)(bb * NKV + h)) * TSEQ + t) * HD + d] = hv;
          }
        }
      }
    }
  } else {
    // V: transpose 128x128 tile through LDS, then coalesced VT stores
    // lCt[col(d) 0..127][row(t) 0..127], stride 136
#pragma unroll
    for (int mi = 0; mi < 4; ++mi)
#pragma unroll
      for (int ni = 0; ni < 4; ++ni)
#pragma unroll
        for (int r = 0; r < 4; ++r)
          lmem[(size_t)(wcol + ni * 16 + l16) * 136 + wrow + mi * 16 + lhi * 4 + r] =
              (__bf16)acc[mi][ni][r];
    __syncthreads();
    const int h = (n0 - 2560) >> 7;
    const size_t vbase = ((size_t)(bb * NKV + h)) * HD * TSEQ;
    const int t0 = m0 & 2047;
#pragma unroll
    for (int it = 0; it < 8; ++it) {
      int d = it * 16 + (tid >> 4);
      int tt = (tid & 15) * 8;
      bf16x8 vv = *reinterpret_cast<const bf16x8*>(&lmem[(size_t)d * 136 + tt]);
      *reinterpret_cast<bf16x8*>(&VT[vbase + (size_t)d * TSEQ + t0 + tt]) = vv;
    }
  }
}

// ---------------------------------------------------------------------------
// Flash attention, sliding window 512, causal, GQA 16/4.
// Block: (b,h, 128 q rows); 4 waves x 32 q rows. KV tiles of 64.
// K,V reg-prefetched (T14); XOR-swizzled LDS (G4); setprio around MFMA (T5).
// V consumed pre-transposed from global: VT[b][kvh][d][T].
// ---------------------------------------------------------------------------
#define SWZ(row, col) ((col) ^ (((row) & 7) << 3))

__global__ __launch_bounds__(256) void k_attn(const __bf16* __restrict__ Q,
                                              const __bf16* __restrict__ K,
                                              const __bf16* __restrict__ VT,
                                              __bf16* __restrict__ Aout) {
  __shared__ __align__(16) __bf16 lK[64 * 128];    // [s][d] swizzled
  __shared__ __align__(16) __bf16 lVt[128 * 64];   // [d][s] swizzled
  __shared__ __align__(16) __bf16 lP[4][32][68];   // per-wave P, stride 68

  const int tid = threadIdx.x, lane = tid & 63, wid = tid >> 6;
  const int l16 = lane & 15, lhi = lane >> 4;
  const int bh = blockIdx.y;
  const int b = bh >> 4, h = bh & 15;
  const int kvh = h >> 2;
  const int qb = 15 - blockIdx.x;  // heavy (large q0) blocks dispatched first
  const int q0 = qb * 128;
  const int qw = q0 + wid * 32;

  const __bf16* Qb = Q + (size_t)bh * TSEQ * HD;
  const __bf16* Kb = K + (size_t)(b * NKV + kvh) * TSEQ * HD;
  const __bf16* Vt = VT + (size_t)(b * NKV + kvh) * HD * TSEQ;

  bf16x8 aq[2][4];
#pragma unroll
  for (int mi = 0; mi < 2; ++mi)
#pragma unroll
    for (int dblk = 0; dblk < 4; ++dblk)
      aq[mi][dblk] = *reinterpret_cast<const bf16x8*>(
          &Qb[(size_t)(qw + mi * 16 + l16) * HD + dblk * 32 + lhi * 8]);

  float mrow[2][4], lrow[2][4];
#pragma unroll
  for (int mi = 0; mi < 2; ++mi)
#pragma unroll
    for (int r = 0; r < 4; ++r) { mrow[mi][r] = -INFINITY; lrow[mi][r] = 0.0f; }
  f32x4 accO[2][8] = {};

  int s_lo = q0 - (WIN - 1);
  if (s_lo < 0) s_lo = 0;
  s_lo &= ~63;
  const int nt = (q0 + 128 - s_lo) >> 6;
  const float scale = 0.08838834764831845f;  // 1/sqrt(128)

  // per-thread staging coords
  const int krow = tid >> 4, kcol = (tid & 15) * 8;   // K: +64 rows per i-step? no: slot
  // prefetch tile 0 into regs
  bf16x8 kreg[4], vreg[4];
#pragma unroll
  for (int i = 0; i < 4; ++i) {
    int slot = tid + i * 256;
    kreg[i] = *reinterpret_cast<const bf16x8*>(
        &Kb[(size_t)(s_lo + (slot >> 4)) * HD + (slot & 15) * 8]);
    vreg[i] = *reinterpret_cast<const bf16x8*>(
        &Vt[(size_t)(slot >> 3) * TSEQ + s_lo + (slot & 7) * 8]);
  }

  for (int t = 0; t < nt; ++t) {
    const int s0 = s_lo + t * 64;
    __syncthreads();  // previous tile's readers done
#pragma unroll
    for (int i = 0; i < 4; ++i) {
      int slot = tid + i * 256;
      int kr = slot >> 4, kc = (slot & 15) * 8;
      *reinterpret_cast<bf16x8*>(&lK[kr * 128 + SWZ(kr, kc)]) = kreg[i];
      int vd = slot >> 3, vc = (slot & 7) * 8;
      *reinterpret_cast<bf16x8*>(&lVt[vd * 64 + SWZ(vd, vc)]) = vreg[i];
    }
    if (t + 1 < nt) {
      const int s1 = s0 + 64;
#pragma unroll
      for (int i = 0; i < 4; ++i) {
        int slot = tid + i * 256;
        kreg[i] = *reinterpret_cast<const bf16x8*>(
            &Kb[(size_t)(s1 + (slot >> 4)) * HD + (slot & 15) * 8]);
        vreg[i] = *reinterpret_cast<const bf16x8*>(
            &Vt[(size_t)(slot >> 3) * TSEQ + s1 + (slot & 7) * 8]);
      }
    }
    __syncthreads();  // LDS ready

    // --- QK^T + online softmax, per 16-row group
#pragma unroll
    for (int mi = 0; mi < 2; ++mi) {
      f32x4 accS[4] = {};
      __builtin_amdgcn_s_setprio(1);
#pragma unroll
      for (int sb = 0; sb < 4; ++sb) {
#pragma unroll
        for (int dblk = 0; dblk < 4; ++dblk) {
          int srow = sb * 16 + l16, scol = dblk * 32 + lhi * 8;
          bf16x8 bk = *reinterpret_cast<const bf16x8*>(&lK[srow * 128 + SWZ(srow, scol)]);
          accS[sb] = __builtin_amdgcn_mfma_f32_16x16x32_bf16(aq[mi][dblk], bk, accS[sb], 0, 0, 0);
        }
      }
      __builtin_amdgcn_s_setprio(0);
#pragma unroll
      for (int r = 0; r < 4; ++r) {
        int qrow = qw + mi * 16 + lhi * 4 + r;
        float vv[4];
        float tmax = -INFINITY;
#pragma unroll
        for (int sb = 0; sb < 4; ++sb) {
          int sc = s0 + sb * 16 + l16;
          float val = accS[sb][r] * scale;
          bool ok = (sc <= qrow) && (qrow - sc < WIN);
          vv[sb] = ok ? val : -INFINITY;
          tmax = fmaxf(tmax, vv[sb]);
        }
#pragma unroll
        for (int off = 1; off < 16; off <<= 1) tmax = fmaxf(tmax, __shfl_xor(tmax, off, 64));
        float mnew = fmaxf(mrow[mi][r], tmax);
        float msafe = (mnew == -INFINITY) ? 0.0f : mnew;
        float corr = (mrow[mi][r] == mnew) ? 1.0f : __expf(mrow[mi][r] - mnew);
        float psum = 0.0f;
#pragma unroll
        for (int sb = 0; sb < 4; ++sb) {
          float p = __expf(vv[sb] - msafe);
          psum += p;
          lP[wid][mi * 16 + lhi * 4 + r][sb * 16 + l16] = (__bf16)p;
        }
#pragma unroll
        for (int off = 1; off < 16; off <<= 1) psum += __shfl_xor(psum, off, 64);
        lrow[mi][r] = lrow[mi][r] * corr + psum;
        mrow[mi][r] = mnew;
#pragma unroll
        for (int ni = 0; ni < 8; ++ni) accO[mi][ni][r] *= corr;
      }
    }

    // --- PV: P (A-frags from lP) x V (B-frags from lVt)
    bf16x8 ap[2][2];
#pragma unroll
    for (int mi = 0; mi < 2; ++mi)
#pragma unroll
      for (int ks = 0; ks < 2; ++ks)
        ap[mi][ks] = *reinterpret_cast<const bf16x8*>(&lP[wid][mi * 16 + l16][ks * 32 + lhi * 8]);
    __builtin_amdgcn_s_setprio(1);
#pragma unroll
    for (int ni = 0; ni < 8; ++ni) {
      int vrow = ni * 16 + l16;
      bf16x8 bv0 = *reinterpret_cast<const bf16x8*>(&lVt[vrow * 64 + SWZ(vrow, lhi * 8)]);
      bf16x8 bv1 = *reinterpret_cast<const bf16x8*>(&lVt[vrow * 64 + SWZ(vrow, 32 + lhi * 8)]);
      accO[0][ni] = __builtin_amdgcn_mfma_f32_16x16x32_bf16(ap[0][0], bv0, accO[0][ni], 0, 0, 0);
      accO[0][ni] = __builtin_amdgcn_mfma_f32_16x16x32_bf16(ap[0][1], bv1, accO[0][ni], 0, 0, 0);
      accO[1][ni] = __builtin_amdgcn_mfma_f32_16x16x32_bf16(ap[1][0], bv0, accO[1][ni], 0, 0, 0);
      accO[1][ni] = __builtin_amdgcn_mfma_f32_16x16x32_bf16(ap[1][1], bv1, accO[1][ni], 0, 0, 0);
    }
    __builtin_amdgcn_s_setprio(0);
  }

#pragma unroll
  for (int mi = 0; mi < 2; ++mi) {
    float invl[4];
#pragma unroll
    for (int r = 0; r < 4; ++r) invl[r] = 1.0f / lrow[mi][r];
#pragma unroll
    for (int ni = 0; ni < 8; ++ni) {
#pragma unroll
      for (int r = 0; r < 4; ++r) {
        int row = qw + mi * 16 + lhi * 4 + r;
        int d = ni * 16 + l16;
        Aout[((size_t)(b * TSEQ + row)) * CDIM + h * HD + d] = (__bf16)(accO[mi][ni][r] * invl[r]);
      }
    }
  }
}

// ---------------------------------------------------------------------------
// Output GEMM + residual (m97 structure): out f32 = x + A @ woT^T
// ---------------------------------------------------------------------------
__global__ __launch_bounds__(256) void k_gemm_out(const __bf16* __restrict__ A,
                                                  const __bf16* __restrict__ woT,
                                                  const float* __restrict__ x,
                                                  float* __restrict__ out) {
  __shared__ __align__(16) __bf16 lA[128 * 32];
  __shared__ __align__(16) __bf16 lB[128 * 32];
  const int tid = threadIdx.x;
  const int lane = tid & 63;
  const int w = tid >> 6;
  const int wrow = (w >> 1) * 64, wcol = (w & 1) * 64;
  const int l16 = lane & 15, lhi = lane >> 4;
  const int grow = lane >> 2;
  const int gcol = (lane & 3) * 8;
  const int m0 = blockIdx.y * 128;
  const int n0 = blockIdx.x * 128;

  f32x4 acc[4][4] = {};

  for (int k0 = 0; k0 < CDIM; k0 += 32) {
#pragma unroll
    for (int i = 0; i < 2; ++i) {
      const int r0 = (w * 2 + i) * 16;
      gl_lds16(&A[(size_t)(m0 + r0 + grow) * CDIM + k0 + gcol], &lA[r0 * 32]);
      gl_lds16(&woT[(size_t)(n0 + r0 + grow) * CDIM + k0 + gcol], &lB[r0 * 32]);
    }
    __syncthreads();
    bf16x8 a[4], b[4];
#pragma unroll
    for (int mi = 0; mi < 4; ++mi)
      a[mi] = *reinterpret_cast<const bf16x8*>(&lA[(wrow + mi * 16 + l16) * 32 + lhi * 8]);
#pragma unroll
    for (int ni = 0; ni < 4; ++ni)
      b[ni] = *reinterpret_cast<const bf16x8*>(&lB[(wcol + ni * 16 + l16) * 32 + lhi * 8]);
#pragma unroll
    for (int mi = 0; mi < 4; ++mi)
#pragma unroll
      for (int ni = 0; ni < 4; ++ni)
        acc[mi][ni] = __builtin_amdgcn_mfma_f32_16x16x32_bf16(a[mi], b[ni], acc[mi][ni], 0, 0, 0);
    __syncthreads();
  }

#pragma unroll
  for (int mi = 0; mi < 4; ++mi) {
#pragma unroll
    for (int ni = 0; ni < 4; ++ni) {
#pragma unroll
      for (int r = 0; r < 4; ++r) {
        int row = m0 + wrow + mi * 16 + lhi * 4 + r;
        int col = n0 + wcol + ni * 16 + l16;
        size_t idx = (size_t)row * CDIM + col;
        out[idx] = x[idx] + acc[mi][ni][r];
      }
    }
  }
}

// ---------------------------------------------------------------------------
extern "C" void kernel_launch(void* const* d_in, const int* in_sizes, int n_in,
                              void* d_out, int out_size, void* d_ws, size_t ws_size,
                              hipStream_t stream) {
  const float* x = (const float*)d_in[0];
  const float* norm_w = (const float*)d_in[1];
  const float* wq = (const float*)d_in[2];
  const float* wk = (const float*)d_in[3];
  const float* wv = (const float*)d_in[4];
  const float* wo = (const float*)d_in[5];
  const float* rc = (const float*)d_in[6];
  const float* rs = (const float*)d_in[7];
  float* out = (float*)d_out;

  char* ws = (char*)d_ws;
  __bf16* xn  = (__bf16*)(ws);              // 4096x2048 bf16 (reused as attn_out)
  __bf16* wqT = (__bf16*)(ws + 16777216);   // 2048x2048
  __bf16* wkT = (__bf16*)(ws + 25165824);   // 512x2048
  __bf16* wvT = (__bf16*)(ws + 27262976);   // 512x2048
  __bf16* woT = (__bf16*)(ws + 29360128);   // 2048x2048
  __bf16* Qb  = (__bf16*)(ws + 37748736);   // 2x16x2048x128
  __bf16* Kb  = (__bf16*)(ws + 54525952);   // 2x4x2048x128
  __bf16* VTb = (__bf16*)(ws + 58720256);   // 2x4x128x2048 (transposed)
  if (ws_size < 62914560) return;

  k_wtrans_all<<<dim3(80, 32), 256, 0, stream>>>(wq, wk, wv, wo, wqT, wkT, wvT, woT);
  k_rmsnorm<<<4096, 256, 0, stream>>>(x, norm_w, xn);
  k_gemm_qkv<<<dim3(24, 32), 256, 0, stream>>>(xn, wqT, wkT, wvT, Qb, Kb, VTb);
  k_rope<<<(BDIM * TSEQ * (NH + NKV)) / 4, 256, 0, stream>>>(Qb, Kb, rc, rs);
  k_attn<<<dim3(16, BDIM * NH), 256, 0, stream>>>(Qb, Kb, VTb, xn);
  k_gemm_out<<<dim3(16, 32), 256, 0, stream>>>(xn, woT, x, out);
}

// Round 4
// 304.837 us; speedup vs baseline: 1.1363x; 1.0851x over previous
//
#include <hip/hip_runtime.h>
#include <hip/hip_bf16.h>

typedef __attribute__((ext_vector_type(8))) __bf16 bf16x8;
typedef __attribute__((ext_vector_type(4))) __bf16 bf16x4;
typedef __attribute__((ext_vector_type(4))) float f32x4;

#define BDIM 2
#define TSEQ 2048
#define CDIM 2048
#define NH 16
#define NKV 4
#define HD 128
#define WIN 512

// async global->LDS, 16B per lane; LDS dest is wave-uniform base + lane*16
__device__ __forceinline__ void gl_lds16(const __bf16* g, __bf16* l) {
  __builtin_amdgcn_global_load_lds(
      (const __attribute__((address_space(1))) void*)g,
      (__attribute__((address_space(3))) void*)l, 16, 0, 0);
}

// ---------------------------------------------------------------------------
// RMSNorm: x (f32 [4096][2048]) -> xn (bf16), one block per row
// ---------------------------------------------------------------------------
__global__ __launch_bounds__(256) void k_rmsnorm(const float* __restrict__ x,
                                                 const float* __restrict__ w,
                                                 __bf16* __restrict__ xn) {
  __shared__ float red[4];
  const int row = blockIdx.x;
  const int tid = threadIdx.x;
  const float* xr = x + (size_t)row * CDIM;
  f32x4 v0 = *reinterpret_cast<const f32x4*>(&xr[tid * 8]);
  f32x4 v1 = *reinterpret_cast<const f32x4*>(&xr[tid * 8 + 4]);
  float s = v0[0] * v0[0] + v0[1] * v0[1] + v0[2] * v0[2] + v0[3] * v0[3] +
            v1[0] * v1[0] + v1[1] * v1[1] + v1[2] * v1[2] + v1[3] * v1[3];
#pragma unroll
  for (int off = 32; off > 0; off >>= 1) s += __shfl_down(s, off, 64);
  if ((tid & 63) == 0) red[tid >> 6] = s;
  __syncthreads();
  float tot = red[0] + red[1] + red[2] + red[3];
  float nrm = rsqrtf(tot * (1.0f / CDIM) + 1e-6f);
  const float* wp = w + tid * 8;
  bf16x8 o;
  o[0] = (__bf16)(v0[0] * nrm * wp[0]);
  o[1] = (__bf16)(v0[1] * nrm * wp[1]);
  o[2] = (__bf16)(v0[2] * nrm * wp[2]);
  o[3] = (__bf16)(v0[3] * nrm * wp[3]);
  o[4] = (__bf16)(v1[0] * nrm * wp[4]);
  o[5] = (__bf16)(v1[1] * nrm * wp[5]);
  o[6] = (__bf16)(v1[2] * nrm * wp[6]);
  o[7] = (__bf16)(v1[3] * nrm * wp[7]);
  *reinterpret_cast<bf16x8*>(&xn[(size_t)row * CDIM + tid * 8]) = o;
}

// ---------------------------------------------------------------------------
// Weight transpose+convert, all 4 weights in ONE launch.
// W f32 [K=2048][N] -> Wt bf16 [N][2048]; 64x64 tile per block.
// blockIdx.x: 0-31 wq | 32-39 wk | 40-47 wv | 48-79 wo
// ---------------------------------------------------------------------------
__global__ __launch_bounds__(256) void k_wtrans_all(
    const float* __restrict__ wq, const float* __restrict__ wk,
    const float* __restrict__ wv, const float* __restrict__ wo,
    __bf16* __restrict__ wqT, __bf16* __restrict__ wkT,
    __bf16* __restrict__ wvT, __bf16* __restrict__ woT) {
  __shared__ float lt[64][65];
  const int bx = blockIdx.x;
  const float* W;
  __bf16* Wt;
  int N, ntile;
  if (bx < 32) { W = wq; Wt = wqT; N = 2048; ntile = bx; }
  else if (bx < 40) { W = wk; Wt = wkT; N = 512; ntile = bx - 32; }
  else if (bx < 48) { W = wv; Wt = wvT; N = 512; ntile = bx - 40; }
  else { W = wo; Wt = woT; N = 2048; ntile = bx - 48; }
  const int tid = threadIdx.x;
  const int n0 = ntile * 64, k0 = blockIdx.y * 64;
  const int tr = tid >> 4, tc = tid & 15;
#pragma unroll
  for (int i = 0; i < 4; ++i) {
    int kr = tr + i * 16;
    f32x4 vv = *reinterpret_cast<const f32x4*>(&W[(size_t)(k0 + kr) * N + n0 + tc * 4]);
    lt[kr][tc * 4 + 0] = vv[0];
    lt[kr][tc * 4 + 1] = vv[1];
    lt[kr][tc * 4 + 2] = vv[2];
    lt[kr][tc * 4 + 3] = vv[3];
  }
  __syncthreads();
#pragma unroll
  for (int i = 0; i < 4; ++i) {
    int nr = tr + i * 16;
    int kc = tc * 4;
    bf16x4 o;
    o[0] = (__bf16)lt[kc + 0][nr];
    o[1] = (__bf16)lt[kc + 1][nr];
    o[2] = (__bf16)lt[kc + 2][nr];
    o[3] = (__bf16)lt[kc + 3][nr];
    *reinterpret_cast<bf16x4*>(&Wt[(size_t)(n0 + nr) * 2048 + k0 + kc]) = o;
  }
}

// ---------------------------------------------------------------------------
// RoPE in-place on Q (bf16 [B][16][T][128]) and K (bf16 [B][4][T][128]).
// ---------------------------------------------------------------------------
__global__ __launch_bounds__(256) void k_rope(__bf16* __restrict__ Q,
                                              __bf16* __restrict__ K,
                                              const float* __restrict__ rc,
                                              const float* __restrict__ rs) {
  int g = blockIdx.x * 4 + (threadIdx.x >> 6);
  int lane = threadIdx.x & 63;
  int b = g / (TSEQ * (NH + NKV));
  int rem = g % (TSEQ * (NH + NKV));
  int t = rem / (NH + NKV);
  int hh = rem % (NH + NKV);
  __bf16* base;
  if (hh < NH)
    base = Q + (((size_t)(b * NH + hh)) * TSEQ + t) * HD;
  else
    base = K + (((size_t)(b * NKV + (hh - NH))) * TSEQ + t) * HD;
  float x1 = (float)base[lane];
  float x2 = (float)base[lane + 64];
  float c = rc[t * 64 + lane];
  float s = rs[t * 64 + lane];
  base[lane] = (__bf16)(x1 * c - x2 * s);
  base[lane + 64] = (__bf16)(x2 * c + x1 * s);
}

// ---------------------------------------------------------------------------
// GEMM QKV (m97 structure): C[4096][3072] = xn @ [wq|wk|wv]^T, B given [N][K].
// ---------------------------------------------------------------------------
__global__ __launch_bounds__(256) void k_gemm_qkv(
    const __bf16* __restrict__ xn, const __bf16* __restrict__ wqT,
    const __bf16* __restrict__ wkT, const __bf16* __restrict__ wvT,
    __bf16* __restrict__ Q, __bf16* __restrict__ K, __bf16* __restrict__ VT) {
  __shared__ __align__(16) __bf16 lmem[128 * 136];
  __bf16* lA = lmem;
  __bf16* lB = lmem + 128 * 32;
  const int tid = threadIdx.x;
  const int lane = tid & 63;
  const int w = tid >> 6;
  const int wrow = (w >> 1) * 64, wcol = (w & 1) * 64;
  const int l16 = lane & 15, lhi = lane >> 4;
  const int grow = lane >> 2;        // 0..15
  const int gcol = (lane & 3) * 8;   // elem offset within BK
  const int m0 = blockIdx.y * 128;
  const int n0 = blockIdx.x * 128;
  const __bf16* wt;
  int nrel;
  if (n0 < 2048) { wt = wqT; nrel = n0; }
  else if (n0 < 2560) { wt = wkT; nrel = n0 - 2048; }
  else { wt = wvT; nrel = n0 - 2560; }

  f32x4 acc[4][4] = {};

  for (int k0 = 0; k0 < CDIM; k0 += 32) {
#pragma unroll
    for (int i = 0; i < 2; ++i) {
      const int r0 = (w * 2 + i) * 16;
      gl_lds16(&xn[(size_t)(m0 + r0 + grow) * CDIM + k0 + gcol], &lA[r0 * 32]);
      gl_lds16(&wt[(size_t)(nrel + r0 + grow) * CDIM + k0 + gcol], &lB[r0 * 32]);
    }
    __syncthreads();
    bf16x8 a[4], b[4];
#pragma unroll
    for (int mi = 0; mi < 4; ++mi)
      a[mi] = *reinterpret_cast<const bf16x8*>(&lA[(wrow + mi * 16 + l16) * 32 + lhi * 8]);
#pragma unroll
    for (int ni = 0; ni < 4; ++ni)
      b[ni] = *reinterpret_cast<const bf16x8*>(&lB[(wcol + ni * 16 + l16) * 32 + lhi * 8]);
#pragma unroll
    for (int mi = 0; mi < 4; ++mi)
#pragma unroll
      for (int ni = 0; ni < 4; ++ni)
        acc[mi][ni] = __builtin_amdgcn_mfma_f32_16x16x32_bf16(a[mi], b[ni], acc[mi][ni], 0, 0, 0);
    __syncthreads();
  }

  const int bb = m0 >> 11;  // batch (rows m0..m0+127 share it)
  if (n0 < 2560) {
#pragma unroll
    for (int mi = 0; mi < 4; ++mi) {
#pragma unroll
      for (int ni = 0; ni < 4; ++ni) {
#pragma unroll
        for (int r = 0; r < 4; ++r) {
          int row = m0 + wrow + mi * 16 + lhi * 4 + r;
          int col = n0 + wcol + ni * 16 + l16;
          int t = row & 2047;
          __bf16 hv = (__bf16)acc[mi][ni][r];
          if (n0 < 2048) {
            int h = col >> 7, d = col & 127;
            Q[(((size_t)(bb * NH + h)) * TSEQ + t) * HD + d] = hv;
          } else {
            int h = (col - 2048) >> 7, d = col & 127;
            K[(((size_t)(bb * NKV + h)) * TSEQ + t) * HD + d] = hv;
          }
        }
      }
    }
  } else {
    // V: transpose 128x128 tile through LDS, then coalesced VT stores
#pragma unroll
    for (int mi = 0; mi < 4; ++mi)
#pragma unroll
      for (int ni = 0; ni < 4; ++ni)
#pragma unroll
        for (int r = 0; r < 4; ++r)
          lmem[(size_t)(wcol + ni * 16 + l16) * 136 + wrow + mi * 16 + lhi * 4 + r] =
              (__bf16)acc[mi][ni][r];
    __syncthreads();
    const int h = (n0 - 2560) >> 7;
    const size_t vbase = ((size_t)(bb * NKV + h)) * HD * TSEQ;
    const int t0 = m0 & 2047;
#pragma unroll
    for (int it = 0; it < 8; ++it) {
      int d = it * 16 + (tid >> 4);
      int tt = (tid & 15) * 8;
      bf16x8 vv = *reinterpret_cast<const bf16x8*>(&lmem[(size_t)d * 136 + tt]);
      *reinterpret_cast<bf16x8*>(&VT[vbase + (size_t)d * TSEQ + t0 + tt]) = vv;
    }
  }
}

// ---------------------------------------------------------------------------
// Flash attention, sliding window 512, causal, GQA 16/4.
// Block: (b,h, 128 q rows); 4 waves x 32 q rows. KV tiles of 64.
// SWAPPED QK^T: S^T = mfma(K_frag, Q_frag) -> lane owns one q-col (l16),
// 16 s-values in registers -> softmax reduce = in-reg + 2 shfl_xor.
// Defer-max (T13, THR=8) skips O-rescale on most tiles.
// ---------------------------------------------------------------------------
#define SWZ(row, col) ((col) ^ (((row) & 7) << 3))
#define LPS 72  // lP row stride (elems)

__global__ __launch_bounds__(256) void k_attn(const __bf16* __restrict__ Q,
                                              const __bf16* __restrict__ K,
                                              const __bf16* __restrict__ VT,
                                              __bf16* __restrict__ Aout) {
  __shared__ __align__(16) __bf16 lK[64 * 128];    // [s][d] swizzled
  __shared__ __align__(16) __bf16 lVt[128 * 64];   // [d][s] swizzled
  __shared__ __align__(16) __bf16 lP[4][32][LPS];  // per-wave P [q][s]

  const int tid = threadIdx.x, lane = tid & 63, wid = tid >> 6;
  const int l16 = lane & 15, lhi = lane >> 4;
  const int bh = blockIdx.y;
  const int b = bh >> 4, h = bh & 15;
  const int kvh = h >> 2;
  const int qb = 15 - blockIdx.x;  // heavy (large q0) blocks dispatched first
  const int q0 = qb * 128;
  const int qw = q0 + wid * 32;

  const __bf16* Qb = Q + (size_t)bh * TSEQ * HD;
  const __bf16* Kb = K + (size_t)(b * NKV + kvh) * TSEQ * HD;
  const __bf16* Vt = VT + (size_t)(b * NKV + kvh) * HD * TSEQ;

  bf16x8 aq[2][4];
#pragma unroll
  for (int mi = 0; mi < 2; ++mi)
#pragma unroll
    for (int dblk = 0; dblk < 4; ++dblk)
      aq[mi][dblk] = *reinterpret_cast<const bf16x8*>(
          &Qb[(size_t)(qw + mi * 16 + l16) * HD + dblk * 32 + lhi * 8]);

  // per-lane softmax state: this lane's q-col = qw + mi*16 + l16
  float mrow[2] = {-INFINITY, -INFINITY};
  float lrow[2] = {0.0f, 0.0f};
  f32x4 accO[2][8] = {};

  int s_lo = q0 - (WIN - 1);
  if (s_lo < 0) s_lo = 0;
  s_lo &= ~63;
  const int nt = (q0 + 128 - s_lo) >> 6;
  const float scale = 0.08838834764831845f;  // 1/sqrt(128)

  // prefetch tile 0 into regs
  bf16x8 kreg[4], vreg[4];
#pragma unroll
  for (int i = 0; i < 4; ++i) {
    int slot = tid + i * 256;
    kreg[i] = *reinterpret_cast<const bf16x8*>(
        &Kb[(size_t)(s_lo + (slot >> 4)) * HD + (slot & 15) * 8]);
    vreg[i] = *reinterpret_cast<const bf16x8*>(
        &Vt[(size_t)(slot >> 3) * TSEQ + s_lo + (slot & 7) * 8]);
  }

  for (int t = 0; t < nt; ++t) {
    const int s0 = s_lo + t * 64;
    __syncthreads();  // previous tile's readers done
#pragma unroll
    for (int i = 0; i < 4; ++i) {
      int slot = tid + i * 256;
      int kr = slot >> 4, kc = (slot & 15) * 8;
      *reinterpret_cast<bf16x8*>(&lK[kr * 128 + SWZ(kr, kc)]) = kreg[i];
      int vd = slot >> 3, vc = (slot & 7) * 8;
      *reinterpret_cast<bf16x8*>(&lVt[vd * 64 + SWZ(vd, vc)]) = vreg[i];
    }
    if (t + 1 < nt) {
      const int s1 = s0 + 64;
#pragma unroll
      for (int i = 0; i < 4; ++i) {
        int slot = tid + i * 256;
        kreg[i] = *reinterpret_cast<const bf16x8*>(
            &Kb[(size_t)(s1 + (slot >> 4)) * HD + (slot & 15) * 8]);
        vreg[i] = *reinterpret_cast<const bf16x8*>(
            &Vt[(size_t)(slot >> 3) * TSEQ + s1 + (slot & 7) * 8]);
      }
    }
    __syncthreads();  // LDS ready

    // --- swapped QK^T: accT[mi][sb] = S^T, rows s (lhi*4+r), cols q (l16)
    f32x4 accT[2][4] = {};
    __builtin_amdgcn_s_setprio(1);
#pragma unroll
    for (int sb = 0; sb < 4; ++sb) {
#pragma unroll
      for (int dblk = 0; dblk < 4; ++dblk) {
        int srow = sb * 16 + l16, scol = dblk * 32 + lhi * 8;
        bf16x8 bk = *reinterpret_cast<const bf16x8*>(&lK[srow * 128 + SWZ(srow, scol)]);
        accT[0][sb] = __builtin_amdgcn_mfma_f32_16x16x32_bf16(bk, aq[0][dblk], accT[0][sb], 0, 0, 0);
        accT[1][sb] = __builtin_amdgcn_mfma_f32_16x16x32_bf16(bk, aq[1][dblk], accT[1][sb], 0, 0, 0);
      }
    }
    __builtin_amdgcn_s_setprio(0);

    // --- softmax per mi group (all in-register along s)
#pragma unroll
    for (int mi = 0; mi < 2; ++mi) {
      const int qrow = qw + mi * 16 + l16;
      float pv[4][4];
      float tmax = -INFINITY;
#pragma unroll
      for (int sb = 0; sb < 4; ++sb) {
#pragma unroll
        for (int r = 0; r < 4; ++r) {
          int sc = s0 + sb * 16 + lhi * 4 + r;
          float val = accT[mi][sb][r] * scale;
          bool ok = (sc <= qrow) && (qrow - sc < WIN);
          val = ok ? val : -INFINITY;
          pv[sb][r] = val;
          tmax = fmaxf(tmax, val);
        }
      }
      tmax = fmaxf(tmax, __shfl_xor(tmax, 16, 64));
      tmax = fmaxf(tmax, __shfl_xor(tmax, 32, 64));

      bool defer = __all(tmax <= mrow[mi] + 8.0f);
      float mnew = mrow[mi];
      if (!defer) {
        mnew = fmaxf(mrow[mi], tmax);
        float corr = (mrow[mi] == mnew) ? 1.0f : __expf(mrow[mi] - mnew);
        mrow[mi] = mnew;
        lrow[mi] *= corr;
        float corrR[4];
#pragma unroll
        for (int r = 0; r < 4; ++r) corrR[r] = __shfl(corr, lhi * 4 + r, 64);
#pragma unroll
        for (int ni = 0; ni < 8; ++ni)
#pragma unroll
          for (int r = 0; r < 4; ++r) accO[mi][ni][r] *= corrR[r];
      }
      float msafe = (mnew == -INFINITY) ? 0.0f : mnew;
      float psum = 0.0f;
#pragma unroll
      for (int sb = 0; sb < 4; ++sb) {
        bf16x4 pk;
#pragma unroll
        for (int r = 0; r < 4; ++r) {
          float p = __expf(pv[sb][r] - msafe);
          psum += p;
          pk[r] = (__bf16)p;
        }
        // s-run of 4 is contiguous: one b64 write
        *reinterpret_cast<bf16x4*>(&lP[wid][mi * 16 + l16][sb * 16 + lhi * 4]) = pk;
      }
      psum += __shfl_xor(psum, 16, 64);
      psum += __shfl_xor(psum, 32, 64);
      lrow[mi] += psum;
    }

    // --- PV: P (A-frags from lP, rows q) x V (B-frags from lVt, rows d)
    bf16x8 ap[2][2];
#pragma unroll
    for (int mi = 0; mi < 2; ++mi)
#pragma unroll
      for (int ks = 0; ks < 2; ++ks)
        ap[mi][ks] = *reinterpret_cast<const bf16x8*>(&lP[wid][mi * 16 + l16][ks * 32 + lhi * 8]);
    __builtin_amdgcn_s_setprio(1);
#pragma unroll
    for (int ni = 0; ni < 8; ++ni) {
      int vrow = ni * 16 + l16;
      bf16x8 bv0 = *reinterpret_cast<const bf16x8*>(&lVt[vrow * 64 + SWZ(vrow, lhi * 8)]);
      bf16x8 bv1 = *reinterpret_cast<const bf16x8*>(&lVt[vrow * 64 + SWZ(vrow, 32 + lhi * 8)]);
      accO[0][ni] = __builtin_amdgcn_mfma_f32_16x16x32_bf16(ap[0][0], bv0, accO[0][ni], 0, 0, 0);
      accO[0][ni] = __builtin_amdgcn_mfma_f32_16x16x32_bf16(ap[0][1], bv1, accO[0][ni], 0, 0, 0);
      accO[1][ni] = __builtin_amdgcn_mfma_f32_16x16x32_bf16(ap[1][0], bv0, accO[1][ni], 0, 0, 0);
      accO[1][ni] = __builtin_amdgcn_mfma_f32_16x16x32_bf16(ap[1][1], bv1, accO[1][ni], 0, 0, 0);
    }
    __builtin_amdgcn_s_setprio(0);
  }

  // epilogue: redistribute 1/l from q-col lanes (l16) to accO rows (lhi*4+r)
#pragma unroll
  for (int mi = 0; mi < 2; ++mi) {
    float invl = 1.0f / lrow[mi];
    float invlR[4];
#pragma unroll
    for (int r = 0; r < 4; ++r) invlR[r] = __shfl(invl, lhi * 4 + r, 64);
#pragma unroll
    for (int ni = 0; ni < 8; ++ni) {
#pragma unroll
      for (int r = 0; r < 4; ++r) {
        int row = qw + mi * 16 + lhi * 4 + r;
        int d = ni * 16 + l16;
        Aout[((size_t)(b * TSEQ + row)) * CDIM + h * HD + d] = (__bf16)(accO[mi][ni][r] * invlR[r]);
      }
    }
  }
}

// ---------------------------------------------------------------------------
// Output GEMM + residual (m97 structure): out f32 = x + A @ woT^T
// ---------------------------------------------------------------------------
__global__ __launch_bounds__(256) void k_gemm_out(const __bf16* __restrict__ A,
                                                  const __bf16* __restrict__ woT,
                                                  const float* __restrict__ x,
                                                  float* __restrict__ out) {
  __shared__ __align__(16) __bf16 lA[128 * 32];
  __shared__ __align__(16) __bf16 lB[128 * 32];
  const int tid = threadIdx.x;
  const int lane = tid & 63;
  const int w = tid >> 6;
  const int wrow = (w >> 1) * 64, wcol = (w & 1) * 64;
  const int l16 = lane & 15, lhi = lane >> 4;
  const int grow = lane >> 2;
  const int gcol = (lane & 3) * 8;
  const int m0 = blockIdx.y * 128;
  const int n0 = blockIdx.x * 128;

  f32x4 acc[4][4] = {};

  for (int k0 = 0; k0 < CDIM; k0 += 32) {
#pragma unroll
    for (int i = 0; i < 2; ++i) {
      const int r0 = (w * 2 + i) * 16;
      gl_lds16(&A[(size_t)(m0 + r0 + grow) * CDIM + k0 + gcol], &lA[r0 * 32]);
      gl_lds16(&woT[(size_t)(n0 + r0 + grow) * CDIM + k0 + gcol], &lB[r0 * 32]);
    }
    __syncthreads();
    bf16x8 a[4], b[4];
#pragma unroll
    for (int mi = 0; mi < 4; ++mi)
      a[mi] = *reinterpret_cast<const bf16x8*>(&lA[(wrow + mi * 16 + l16) * 32 + lhi * 8]);
#pragma unroll
    for (int ni = 0; ni < 4; ++ni)
      b[ni] = *reinterpret_cast<const bf16x8*>(&lB[(wcol + ni * 16 + l16) * 32 + lhi * 8]);
#pragma unroll
    for (int mi = 0; mi < 4; ++mi)
#pragma unroll
      for (int ni = 0; ni < 4; ++ni)
        acc[mi][ni] = __builtin_amdgcn_mfma_f32_16x16x32_bf16(a[mi], b[ni], acc[mi][ni], 0, 0, 0);
    __syncthreads();
  }

#pragma unroll
  for (int mi = 0; mi < 4; ++mi) {
#pragma unroll
    for (int ni = 0; ni < 4; ++ni) {
#pragma unroll
      for (int r = 0; r < 4; ++r) {
        int row = m0 + wrow + mi * 16 + lhi * 4 + r;
        int col = n0 + wcol + ni * 16 + l16;
        size_t idx = (size_t)row * CDIM + col;
        out[idx] = x[idx] + acc[mi][ni][r];
      }
    }
  }
}

// ---------------------------------------------------------------------------
extern "C" void kernel_launch(void* const* d_in, const int* in_sizes, int n_in,
                              void* d_out, int out_size, void* d_ws, size_t ws_size,
                              hipStream_t stream) {
  const float* x = (const float*)d_in[0];
  const float* norm_w = (const float*)d_in[1];
  const float* wq = (const float*)d_in[2];
  const float* wk = (const float*)d_in[3];
  const float* wv = (const float*)d_in[4];
  const float* wo = (const float*)d_in[5];
  const float* rc = (const float*)d_in[6];
  const float* rs = (const float*)d_in[7];
  float* out = (float*)d_out;

  char* ws = (char*)d_ws;
  __bf16* xn  = (__bf16*)(ws);              // 4096x2048 bf16 (reused as attn_out)
  __bf16* wqT = (__bf16*)(ws + 16777216);   // 2048x2048
  __bf16* wkT = (__bf16*)(ws + 25165824);   // 512x2048
  __bf16* wvT = (__bf16*)(ws + 27262976);   // 512x2048
  __bf16* woT = (__bf16*)(ws + 29360128);   // 2048x2048
  __bf16* Qb  = (__bf16*)(ws + 37748736);   // 2x16x2048x128
  __bf16* Kb  = (__bf16*)(ws + 54525952);   // 2x4x2048x128
  __bf16* VTb = (__bf16*)(ws + 58720256);   // 2x4x128x2048 (transposed)
  if (ws_size < 62914560) return;

  k_wtrans_all<<<dim3(80, 32), 256, 0, stream>>>(wq, wk, wv, wo, wqT, wkT, wvT, woT);
  k_rmsnorm<<<4096, 256, 0, stream>>>(x, norm_w, xn);
  k_gemm_qkv<<<dim3(24, 32), 256, 0, stream>>>(xn, wqT, wkT, wvT, Qb, Kb, VTb);
  k_rope<<<(BDIM * TSEQ * (NH + NKV)) / 4, 256, 0, stream>>>(Qb, Kb, rc, rs);
  k_attn<<<dim3(16, BDIM * NH), 256, 0, stream>>>(Qb, Kb, VTb, xn);
  k_gemm_out<<<dim3(16, 32), 256, 0, stream>>>(xn, woT, x, out);
}

// Round 5
// 276.607 us; speedup vs baseline: 1.2523x; 1.1021x over previous
//
#include <hip/hip_runtime.h>
#include <hip/hip_bf16.h>

typedef __attribute__((ext_vector_type(8))) __bf16 bf16x8;
typedef __attribute__((ext_vector_type(4))) __bf16 bf16x4;
typedef __attribute__((ext_vector_type(4))) float f32x4;

#define BDIM 2
#define TSEQ 2048
#define CDIM 2048
#define NH 16
#define NKV 4
#define HD 128
#define WIN 512

// async global->LDS, 16B per lane; LDS dest is wave-uniform base + lane*16
__device__ __forceinline__ void gl_lds16(const __bf16* g, __bf16* l) {
  __builtin_amdgcn_global_load_lds(
      (const __attribute__((address_space(1))) void*)g,
      (__attribute__((address_space(3))) void*)l, 16, 0, 0);
}

// ---------------------------------------------------------------------------
// RMSNorm: x (f32 [4096][2048]) -> xn (bf16), one block per row
// ---------------------------------------------------------------------------
__global__ __launch_bounds__(256) void k_rmsnorm(const float* __restrict__ x,
                                                 const float* __restrict__ w,
                                                 __bf16* __restrict__ xn) {
  __shared__ float red[4];
  const int row = blockIdx.x;
  const int tid = threadIdx.x;
  const float* xr = x + (size_t)row * CDIM;
  f32x4 v0 = *reinterpret_cast<const f32x4*>(&xr[tid * 8]);
  f32x4 v1 = *reinterpret_cast<const f32x4*>(&xr[tid * 8 + 4]);
  float s = v0[0] * v0[0] + v0[1] * v0[1] + v0[2] * v0[2] + v0[3] * v0[3] +
            v1[0] * v1[0] + v1[1] * v1[1] + v1[2] * v1[2] + v1[3] * v1[3];
#pragma unroll
  for (int off = 32; off > 0; off >>= 1) s += __shfl_down(s, off, 64);
  if ((tid & 63) == 0) red[tid >> 6] = s;
  __syncthreads();
  float tot = red[0] + red[1] + red[2] + red[3];
  float nrm = rsqrtf(tot * (1.0f / CDIM) + 1e-6f);
  const float* wp = w + tid * 8;
  bf16x8 o;
  o[0] = (__bf16)(v0[0] * nrm * wp[0]);
  o[1] = (__bf16)(v0[1] * nrm * wp[1]);
  o[2] = (__bf16)(v0[2] * nrm * wp[2]);
  o[3] = (__bf16)(v0[3] * nrm * wp[3]);
  o[4] = (__bf16)(v1[0] * nrm * wp[4]);
  o[5] = (__bf16)(v1[1] * nrm * wp[5]);
  o[6] = (__bf16)(v1[2] * nrm * wp[6]);
  o[7] = (__bf16)(v1[3] * nrm * wp[7]);
  *reinterpret_cast<bf16x8*>(&xn[(size_t)row * CDIM + tid * 8]) = o;
}

// ---------------------------------------------------------------------------
// Weight transpose+convert, all 4 weights in ONE launch.
// W f32 [K=2048][N] -> Wt bf16 [N][2048]; 64x64 tile per block.
// ---------------------------------------------------------------------------
__global__ __launch_bounds__(256) void k_wtrans_all(
    const float* __restrict__ wq, const float* __restrict__ wk,
    const float* __restrict__ wv, const float* __restrict__ wo,
    __bf16* __restrict__ wqT, __bf16* __restrict__ wkT,
    __bf16* __restrict__ wvT, __bf16* __restrict__ woT) {
  __shared__ float lt[64][65];
  const int bx = blockIdx.x;
  const float* W;
  __bf16* Wt;
  int N, ntile;
  if (bx < 32) { W = wq; Wt = wqT; N = 2048; ntile = bx; }
  else if (bx < 40) { W = wk; Wt = wkT; N = 512; ntile = bx - 32; }
  else if (bx < 48) { W = wv; Wt = wvT; N = 512; ntile = bx - 40; }
  else { W = wo; Wt = woT; N = 2048; ntile = bx - 48; }
  const int tid = threadIdx.x;
  const int n0 = ntile * 64, k0 = blockIdx.y * 64;
  const int tr = tid >> 4, tc = tid & 15;
#pragma unroll
  for (int i = 0; i < 4; ++i) {
    int kr = tr + i * 16;
    f32x4 vv = *reinterpret_cast<const f32x4*>(&W[(size_t)(k0 + kr) * N + n0 + tc * 4]);
    lt[kr][tc * 4 + 0] = vv[0];
    lt[kr][tc * 4 + 1] = vv[1];
    lt[kr][tc * 4 + 2] = vv[2];
    lt[kr][tc * 4 + 3] = vv[3];
  }
  __syncthreads();
#pragma unroll
  for (int i = 0; i < 4; ++i) {
    int nr = tr + i * 16;
    int kc = tc * 4;
    bf16x4 o;
    o[0] = (__bf16)lt[kc + 0][nr];
    o[1] = (__bf16)lt[kc + 1][nr];
    o[2] = (__bf16)lt[kc + 2][nr];
    o[3] = (__bf16)lt[kc + 3][nr];
    *reinterpret_cast<bf16x4*>(&Wt[(size_t)(n0 + nr) * 2048 + k0 + kc]) = o;
  }
}

// ---------------------------------------------------------------------------
// GEMM QKV (m97 structure) with FUSED RoPE epilogue.
// C[4096][3072] = xn @ [wq|wk|wv]^T, B given [N][K]. 128x128 tile, BK=32.
// Wave decomposition 4x1 (per-wave 32 rows x 128 cols) so RoPE pairs
// (d, d+64) = (ni, ni+4) live in the same lane: rotation is register math.
// Q,K stored rotated; V stored TRANSPOSED (b,h,d,t) via LDS transpose.
// ---------------------------------------------------------------------------
__global__ __launch_bounds__(256) void k_gemm_qkv(
    const __bf16* __restrict__ xn, const __bf16* __restrict__ wqT,
    const __bf16* __restrict__ wkT, const __bf16* __restrict__ wvT,
    const float* __restrict__ rc, const float* __restrict__ rs,
    __bf16* __restrict__ Q, __bf16* __restrict__ K, __bf16* __restrict__ VT) {
  __shared__ __align__(16) __bf16 lmem[128 * 136];
  __bf16* lA = lmem;
  __bf16* lB = lmem + 128 * 32;
  const int tid = threadIdx.x;
  const int lane = tid & 63;
  const int w = tid >> 6;
  const int wrow = w * 32;  // 4x1 wave layout
  const int l16 = lane & 15, lhi = lane >> 4;
  const int grow = lane >> 2;        // 0..15
  const int gcol = (lane & 3) * 8;   // elem offset within BK
  const int m0 = blockIdx.y * 128;
  const int n0 = blockIdx.x * 128;
  const __bf16* wt;
  int nrel;
  if (n0 < 2048) { wt = wqT; nrel = n0; }
  else if (n0 < 2560) { wt = wkT; nrel = n0 - 2048; }
  else { wt = wvT; nrel = n0 - 2560; }

  f32x4 acc[2][8] = {};

  for (int k0 = 0; k0 < CDIM; k0 += 32) {
#pragma unroll
    for (int i = 0; i < 2; ++i) {
      const int r0 = (w * 2 + i) * 16;
      gl_lds16(&xn[(size_t)(m0 + r0 + grow) * CDIM + k0 + gcol], &lA[r0 * 32]);
      gl_lds16(&wt[(size_t)(nrel + r0 + grow) * CDIM + k0 + gcol], &lB[r0 * 32]);
    }
    __syncthreads();
    bf16x8 a[2], b[8];
#pragma unroll
    for (int mi = 0; mi < 2; ++mi)
      a[mi] = *reinterpret_cast<const bf16x8*>(&lA[(wrow + mi * 16 + l16) * 32 + lhi * 8]);
#pragma unroll
    for (int ni = 0; ni < 8; ++ni)
      b[ni] = *reinterpret_cast<const bf16x8*>(&lB[(ni * 16 + l16) * 32 + lhi * 8]);
#pragma unroll
    for (int mi = 0; mi < 2; ++mi)
#pragma unroll
      for (int ni = 0; ni < 8; ++ni)
        acc[mi][ni] = __builtin_amdgcn_mfma_f32_16x16x32_bf16(a[mi], b[ni], acc[mi][ni], 0, 0, 0);
    __syncthreads();
  }

  const int bb = m0 >> 11;  // batch (rows m0..m0+127 share it)
  if (n0 < 2560) {
    // Q or K tile (one head's 128 dims): fused RoPE + store
    const bool isQ = (n0 < 2048);
    const int h = isQ ? (n0 >> 7) : ((n0 - 2048) >> 7);
    __bf16* outb = isQ ? (Q + (((size_t)(bb * NH + h)) * TSEQ) * HD)
                       : (K + (((size_t)(bb * NKV + h)) * TSEQ) * HD);
#pragma unroll
    for (int mi = 0; mi < 2; ++mi) {
#pragma unroll
      for (int r = 0; r < 4; ++r) {
        int row = m0 + wrow + mi * 16 + lhi * 4 + r;
        int t = row & 2047;
        __bf16* op = outb + (size_t)t * HD;
        const float* cp = rc + t * 64;
        const float* sp = rs + t * 64;
#pragma unroll
        for (int ni = 0; ni < 4; ++ni) {
          int d = ni * 16 + l16;
          float c = cp[d], s = sp[d];
          float x1 = acc[mi][ni][r];
          float x2 = acc[mi][ni + 4][r];
          op[d] = (__bf16)(x1 * c - x2 * s);
          op[d + 64] = (__bf16)(x2 * c + x1 * s);
        }
      }
    }
  } else {
    // V: transpose 128x128 tile through LDS, then coalesced VT stores
#pragma unroll
    for (int mi = 0; mi < 2; ++mi)
#pragma unroll
      for (int ni = 0; ni < 8; ++ni)
#pragma unroll
        for (int r = 0; r < 4; ++r)
          lmem[(size_t)(ni * 16 + l16) * 136 + wrow + mi * 16 + lhi * 4 + r] =
              (__bf16)acc[mi][ni][r];
    __syncthreads();
    const int h = (n0 - 2560) >> 7;
    const size_t vbase = ((size_t)(bb * NKV + h)) * HD * TSEQ;
    const int t0 = m0 & 2047;
#pragma unroll
    for (int it = 0; it < 8; ++it) {
      int d = it * 16 + (tid >> 4);
      int tt = (tid & 15) * 8;
      bf16x8 vv = *reinterpret_cast<const bf16x8*>(&lmem[(size_t)d * 136 + tt]);
      *reinterpret_cast<bf16x8*>(&VT[vbase + (size_t)d * TSEQ + t0 + tt]) = vv;
    }
  }
}

// ---------------------------------------------------------------------------
// Flash attention, sliding window 512, causal, GQA 16/4.
// Block: (b,h, 128 q rows); 8 waves x 16 q rows (512 thr) for occupancy.
// SWAPPED QK^T: S^T = mfma(K_frag, Q_frag) -> lane owns one q-col (l16),
// 16 s-values in registers -> softmax reduce = in-reg + 2 shfl_xor.
// Defer-max (T13, THR=8); K,V reg-prefetch (T14); XOR-swizzled LDS (G4).
// ---------------------------------------------------------------------------
#define SWZ(row, col) ((col) ^ (((row) & 7) << 3))
#define LPS 72  // lP row stride (elems)

__global__ __launch_bounds__(512, 4) void k_attn(const __bf16* __restrict__ Q,
                                                 const __bf16* __restrict__ K,
                                                 const __bf16* __restrict__ VT,
                                                 __bf16* __restrict__ Aout) {
  __shared__ __align__(16) __bf16 lK[64 * 128];    // [s][d] swizzled
  __shared__ __align__(16) __bf16 lVt[128 * 64];   // [d][s] swizzled
  __shared__ __align__(16) __bf16 lP[8][16][LPS];  // per-wave P [q][s]

  const int tid = threadIdx.x, lane = tid & 63, wid = tid >> 6;
  const int l16 = lane & 15, lhi = lane >> 4;
  const int bh = blockIdx.y;
  const int b = bh >> 4, h = bh & 15;
  const int kvh = h >> 2;
  const int qb = 15 - blockIdx.x;  // heavy (large q0) blocks dispatched first
  const int q0 = qb * 128;
  const int qw = q0 + wid * 16;

  const __bf16* Qb = Q + (size_t)bh * TSEQ * HD;
  const __bf16* Kb = K + (size_t)(b * NKV + kvh) * TSEQ * HD;
  const __bf16* Vt = VT + (size_t)(b * NKV + kvh) * HD * TSEQ;

  bf16x8 aq[4];
#pragma unroll
  for (int dblk = 0; dblk < 4; ++dblk)
    aq[dblk] = *reinterpret_cast<const bf16x8*>(
        &Qb[(size_t)(qw + l16) * HD + dblk * 32 + lhi * 8]);

  // per-lane softmax state: this lane's q-col = qw + l16
  float mrow = -INFINITY;
  float lrow = 0.0f;
  f32x4 accO[8] = {};

  int s_lo = q0 - (WIN - 1);
  if (s_lo < 0) s_lo = 0;
  s_lo &= ~63;
  const int nt = (q0 + 128 - s_lo) >> 6;
  const float scale = 0.08838834764831845f;  // 1/sqrt(128)

  // prefetch tile 0 into regs (2 loads/thread at 512 threads)
  bf16x8 kreg[2], vreg[2];
#pragma unroll
  for (int i = 0; i < 2; ++i) {
    int slot = tid + i * 512;
    kreg[i] = *reinterpret_cast<const bf16x8*>(
        &Kb[(size_t)(s_lo + (slot >> 4)) * HD + (slot & 15) * 8]);
    vreg[i] = *reinterpret_cast<const bf16x8*>(
        &Vt[(size_t)(slot >> 3) * TSEQ + s_lo + (slot & 7) * 8]);
  }

  for (int t = 0; t < nt; ++t) {
    const int s0 = s_lo + t * 64;
    __syncthreads();  // previous tile's readers done
#pragma unroll
    for (int i = 0; i < 2; ++i) {
      int slot = tid + i * 512;
      int kr = slot >> 4, kc = (slot & 15) * 8;
      *reinterpret_cast<bf16x8*>(&lK[kr * 128 + SWZ(kr, kc)]) = kreg[i];
      int vd = slot >> 3, vc = (slot & 7) * 8;
      *reinterpret_cast<bf16x8*>(&lVt[vd * 64 + SWZ(vd, vc)]) = vreg[i];
    }
    if (t + 1 < nt) {
      const int s1 = s0 + 64;
#pragma unroll
      for (int i = 0; i < 2; ++i) {
        int slot = tid + i * 512;
        kreg[i] = *reinterpret_cast<const bf16x8*>(
            &Kb[(size_t)(s1 + (slot >> 4)) * HD + (slot & 15) * 8]);
        vreg[i] = *reinterpret_cast<const bf16x8*>(
            &Vt[(size_t)(slot >> 3) * TSEQ + s1 + (slot & 7) * 8]);
      }
    }
    __syncthreads();  // LDS ready

    // --- swapped QK^T: accT[sb] = S^T, rows s (lhi*4+r), cols q (l16)
    f32x4 accT[4] = {};
    __builtin_amdgcn_s_setprio(1);
#pragma unroll
    for (int sb = 0; sb < 4; ++sb) {
#pragma unroll
      for (int dblk = 0; dblk < 4; ++dblk) {
        int srow = sb * 16 + l16, scol = dblk * 32 + lhi * 8;
        bf16x8 bk = *reinterpret_cast<const bf16x8*>(&lK[srow * 128 + SWZ(srow, scol)]);
        accT[sb] = __builtin_amdgcn_mfma_f32_16x16x32_bf16(bk, aq[dblk], accT[sb], 0, 0, 0);
      }
    }
    __builtin_amdgcn_s_setprio(0);

    // --- softmax (all in-register along s)
    {
      const int qrow = qw + l16;
      float pv[4][4];
      float tmax = -INFINITY;
#pragma unroll
      for (int sb = 0; sb < 4; ++sb) {
#pragma unroll
        for (int r = 0; r < 4; ++r) {
          int sc = s0 + sb * 16 + lhi * 4 + r;
          float val = accT[sb][r] * scale;
          bool ok = (sc <= qrow) && (qrow - sc < WIN);
          val = ok ? val : -INFINITY;
          pv[sb][r] = val;
          tmax = fmaxf(tmax, val);
        }
      }
      tmax = fmaxf(tmax, __shfl_xor(tmax, 16, 64));
      tmax = fmaxf(tmax, __shfl_xor(tmax, 32, 64));

      bool defer = __all(tmax <= mrow + 8.0f);
      float mnew = mrow;
      if (!defer) {
        mnew = fmaxf(mrow, tmax);
        float corr = (mrow == mnew) ? 1.0f : __expf(mrow - mnew);
        mrow = mnew;
        lrow *= corr;
        float corrR[4];
#pragma unroll
        for (int r = 0; r < 4; ++r) corrR[r] = __shfl(corr, lhi * 4 + r, 64);
#pragma unroll
        for (int ni = 0; ni < 8; ++ni)
#pragma unroll
          for (int r = 0; r < 4; ++r) accO[ni][r] *= corrR[r];
      }
      float msafe = (mnew == -INFINITY) ? 0.0f : mnew;
      float psum = 0.0f;
#pragma unroll
      for (int sb = 0; sb < 4; ++sb) {
        bf16x4 pk;
#pragma unroll
        for (int r = 0; r < 4; ++r) {
          float p = __expf(pv[sb][r] - msafe);
          psum += p;
          pk[r] = (__bf16)p;
        }
        // s-run of 4 is contiguous: one b64 write
        *reinterpret_cast<bf16x4*>(&lP[wid][l16][sb * 16 + lhi * 4]) = pk;
      }
      psum += __shfl_xor(psum, 16, 64);
      psum += __shfl_xor(psum, 32, 64);
      lrow += psum;
    }

    // --- PV: P (A-frags from lP, rows q) x V (B-frags from lVt, rows d)
    bf16x8 ap[2];
#pragma unroll
    for (int ks = 0; ks < 2; ++ks)
      ap[ks] = *reinterpret_cast<const bf16x8*>(&lP[wid][l16][ks * 32 + lhi * 8]);
    __builtin_amdgcn_s_setprio(1);
#pragma unroll
    for (int ni = 0; ni < 8; ++ni) {
      int vrow = ni * 16 + l16;
      bf16x8 bv0 = *reinterpret_cast<const bf16x8*>(&lVt[vrow * 64 + SWZ(vrow, lhi * 8)]);
      bf16x8 bv1 = *reinterpret_cast<const bf16x8*>(&lVt[vrow * 64 + SWZ(vrow, 32 + lhi * 8)]);
      accO[ni] = __builtin_amdgcn_mfma_f32_16x16x32_bf16(ap[0], bv0, accO[ni], 0, 0, 0);
      accO[ni] = __builtin_amdgcn_mfma_f32_16x16x32_bf16(ap[1], bv1, accO[ni], 0, 0, 0);
    }
    __builtin_amdgcn_s_setprio(0);
  }

  // epilogue: redistribute 1/l from q-col lanes (l16) to accO rows (lhi*4+r)
  {
    float invl = 1.0f / lrow;
    float invlR[4];
#pragma unroll
    for (int r = 0; r < 4; ++r) invlR[r] = __shfl(invl, lhi * 4 + r, 64);
#pragma unroll
    for (int ni = 0; ni < 8; ++ni) {
#pragma unroll
      for (int r = 0; r < 4; ++r) {
        int row = qw + lhi * 4 + r;
        int d = ni * 16 + l16;
        Aout[((size_t)(b * TSEQ + row)) * CDIM + h * HD + d] = (__bf16)(accO[ni][r] * invlR[r]);
      }
    }
  }
}

// ---------------------------------------------------------------------------
// Output GEMM + residual (m97 structure): out f32 = x + A @ woT^T
// ---------------------------------------------------------------------------
__global__ __launch_bounds__(256) void k_gemm_out(const __bf16* __restrict__ A,
                                                  const __bf16* __restrict__ woT,
                                                  const float* __restrict__ x,
                                                  float* __restrict__ out) {
  __shared__ __align__(16) __bf16 lA[128 * 32];
  __shared__ __align__(16) __bf16 lB[128 * 32];
  const int tid = threadIdx.x;
  const int lane = tid & 63;
  const int w = tid >> 6;
  const int wrow = (w >> 1) * 64, wcol = (w & 1) * 64;
  const int l16 = lane & 15, lhi = lane >> 4;
  const int grow = lane >> 2;
  const int gcol = (lane & 3) * 8;
  const int m0 = blockIdx.y * 128;
  const int n0 = blockIdx.x * 128;

  f32x4 acc[4][4] = {};

  for (int k0 = 0; k0 < CDIM; k0 += 32) {
#pragma unroll
    for (int i = 0; i < 2; ++i) {
      const int r0 = (w * 2 + i) * 16;
      gl_lds16(&A[(size_t)(m0 + r0 + grow) * CDIM + k0 + gcol], &lA[r0 * 32]);
      gl_lds16(&woT[(size_t)(n0 + r0 + grow) * CDIM + k0 + gcol], &lB[r0 * 32]);
    }
    __syncthreads();
    bf16x8 a[4], b[4];
#pragma unroll
    for (int mi = 0; mi < 4; ++mi)
      a[mi] = *reinterpret_cast<const bf16x8*>(&lA[(wrow + mi * 16 + l16) * 32 + lhi * 8]);
#pragma unroll
    for (int ni = 0; ni < 4; ++ni)
      b[ni] = *reinterpret_cast<const bf16x8*>(&lB[(wcol + ni * 16 + l16) * 32 + lhi * 8]);
#pragma unroll
    for (int mi = 0; mi < 4; ++mi)
#pragma unroll
      for (int ni = 0; ni < 4; ++ni)
        acc[mi][ni] = __builtin_amdgcn_mfma_f32_16x16x32_bf16(a[mi], b[ni], acc[mi][ni], 0, 0, 0);
    __syncthreads();
  }

#pragma unroll
  for (int mi = 0; mi < 4; ++mi) {
#pragma unroll
    for (int ni = 0; ni < 4; ++ni) {
#pragma unroll
      for (int r = 0; r < 4; ++r) {
        int row = m0 + wrow + mi * 16 + lhi * 4 + r;
        int col = n0 + wcol + ni * 16 + l16;
        size_t idx = (size_t)row * CDIM + col;
        out[idx] = x[idx] + acc[mi][ni][r];
      }
    }
  }
}

// ---------------------------------------------------------------------------
extern "C" void kernel_launch(void* const* d_in, const int* in_sizes, int n_in,
                              void* d_out, int out_size, void* d_ws, size_t ws_size,
                              hipStream_t stream) {
  const float* x = (const float*)d_in[0];
  const float* norm_w = (const float*)d_in[1];
  const float* wq = (const float*)d_in[2];
  const float* wk = (const float*)d_in[3];
  const float* wv = (const float*)d_in[4];
  const float* wo = (const float*)d_in[5];
  const float* rc = (const float*)d_in[6];
  const float* rs = (const float*)d_in[7];
  float* out = (float*)d_out;

  char* ws = (char*)d_ws;
  __bf16* xn  = (__bf16*)(ws);              // 4096x2048 bf16 (reused as attn_out)
  __bf16* wqT = (__bf16*)(ws + 16777216);   // 2048x2048
  __bf16* wkT = (__bf16*)(ws + 25165824);   // 512x2048
  __bf16* wvT = (__bf16*)(ws + 27262976);   // 512x2048
  __bf16* woT = (__bf16*)(ws + 29360128);   // 2048x2048
  __bf16* Qb  = (__bf16*)(ws + 37748736);   // 2x16x2048x128
  __bf16* Kb  = (__bf16*)(ws + 54525952);   // 2x4x2048x128
  __bf16* VTb = (__bf16*)(ws + 58720256);   // 2x4x128x2048 (transposed)
  if (ws_size < 62914560) return;

  k_wtrans_all<<<dim3(80, 32), 256, 0, stream>>>(wq, wk, wv, wo, wqT, wkT, wvT, woT);
  k_rmsnorm<<<4096, 256, 0, stream>>>(x, norm_w, xn);
  k_gemm_qkv<<<dim3(24, 32), 256, 0, stream>>>(xn, wqT, wkT, wvT, rc, rs, Qb, Kb, VTb);
  k_attn<<<dim3(16, BDIM * NH), 512, 0, stream>>>(Qb, Kb, VTb, xn);
  k_gemm_out<<<dim3(16, 32), 256, 0, stream>>>(xn, woT, x, out);
}